// Round 6
// baseline (288.154 us; speedup 1.0000x reference)
//
#include <hip/hip_runtime.h>
#include <math.h>

#define BB 128
#define MM 35
#define PSZ 224
#define PP (PSZ*PSZ)          // 50176
#define SIGN_PENALTY 10.0f
#define RECON_WEIGHT 0.4f
#define DEFOCUS_RAD 1.0f
#define EPS_F 1e-8f
#define INV2PI 0.15915494309189535f

// CT: 224 = 14*16.  n = 14*n2 + n1; k = 16*k1 + k2.
// R18 = R17 post-mortem fixes:
//   k_phase: R17 halved wave count (1.5 waves/SIMD) -> zern load latency
//            un-hidden; the LDS-issue win was canceled. Fix: keep 2px/thread
//            but software-pipeline zern loads (prefetch chunk k+1's 8 loads
//            before chunk k's 256-FMA block: ~512cyc compute covers latency
//            via ILP at low occupancy). 256 thr, grid (99,4), x==98 special.
//   k_final DELETED: folded into stage2 via last-block pattern (int counter
//            at ws_i[8], zeroed by k_phase special block which precedes
//            stage2 in stream order; __threadfence release/acquire; ONE int
//            atomicAdd per block — not a contended float finale, per R5-R7).
//            Saves the serialized 1-block kernel dispatch+drain (~3-4us).
// Budget model: harness poison fills (~41us each) are a fixed ~110us floor in
// the timed window; kernels sum ~30-40us. Diminishing-returns regime.
// Prior structure: separable defocus tables (ws[16..960)); stage1 one plane
// per block grid (14,2,BB), (256,5); tile-major T [img][tile14][h224][c16];
// stage2 global-direct + in-reg loss; v_cvt_pk_bf16_f32 packing.
// Spill rule (R10/R11): >~32 floats cross-phase state = scratch.

// ws layout (floats):
//   [1] z_loss  [2..4] mask^2 partials (3)  [8] done-counter (int)
//   [16..464)  ctab: 224 x float2 e^{i(2D vx^2 - D)}
//   [512..960) rtab: 224 x float2 e^{i(2D vy^2)}
//   [2048 ..) field [B][P][P] packed bf16x2 — dead after stage1; partials alias
//   [T_OFF ..) T [2*B][14][224][16] packed bf16x2
#define WS_PHASE_OFF    2048
#define WS_T_OFF        (WS_PHASE_OFF + BB*PP)
#define N_PARTIALS      (14*BB*2)
#define S1 233            // stage1 LDS row stride (dwords) — odd: 2-way banks
#define S2 20             // stage2 LDS slot-row stride (dwords)

static constexpr float W16R[16] = {
    1.0f, 0.9238795325f, 0.7071067812f, 0.3826834324f, 0.0f,
    -0.3826834324f, -0.7071067812f, -0.9238795325f, -1.0f,
    -0.9238795325f, -0.7071067812f, -0.3826834324f, 0.0f,
    0.3826834324f, 0.7071067812f, 0.9238795325f};
static constexpr float W16I[16] = {
    0.0f, -0.3826834324f, -0.7071067812f, -0.9238795325f, -1.0f,
    -0.9238795325f, -0.7071067812f, -0.3826834324f, 0.0f,
    0.3826834324f, 0.7071067812f, 0.9238795325f, 1.0f,
    0.9238795325f, 0.7071067812f, 0.3826834324f};
static constexpr float W7R[7] = {
    1.0f, 0.6234898019f, -0.2225209340f, -0.9009688679f,
    -0.9009688679f, -0.2225209340f, 0.6234898019f};
static constexpr float W7I[7] = {
    0.0f, -0.7818314825f, -0.9749279122f, -0.4338837391f,
    0.4338837391f, 0.9749279122f, 0.7818314825f};
static constexpr float W14R[7] = {
    1.0f, 0.9009688679f, 0.6234898019f, 0.2225209340f, -0.2225209340f,
    -0.6234898019f, -0.9009688679f};
static constexpr float W14I[7] = {
    0.0f, -0.4338837391f, -0.7818314825f, -0.9749279122f, -0.9749279122f,
    -0.7818314825f, -0.4338837391f};

__device__ __forceinline__ float lincoord(int i) {
    return -1.0f + 2.0f * (float)i / (float)(PSZ - 1);
}
__device__ __forceinline__ void fast_sincos(float x, float* s, float* c) {
    float rv = x * INV2PI;
    rv -= floorf(rv);
    *s = __builtin_amdgcn_sinf(rv);
    *c = __builtin_amdgcn_cosf(rv);
}
__device__ __forceinline__ float2 wexp_neg(float frac) {
    float rv = -frac;
    rv -= floorf(rv);
    return make_float2(__builtin_amdgcn_cosf(rv), __builtin_amdgcn_sinf(rv));
}
__device__ __forceinline__ unsigned pack_bf2(float a, float b) {
    // D[15:0]=bf16(a), D[31:16]=bf16(b) — single VALU op (RNE)
    unsigned r;
    asm("v_cvt_pk_bf16_f32 %0, %1, %2" : "=v"(r) : "v"(a), "v"(b));
    return r;
}
__device__ __forceinline__ float2 unpack_bf2(unsigned v) {
    return make_float2(__uint_as_float(v << 16), __uint_as_float(v & 0xffff0000u));
}
__device__ __forceinline__ float2 cmul(float2 a, float2 b) {
    return make_float2(fmaf(a.x, b.x, -a.y * b.y), fmaf(a.x, b.y, a.y * b.x));
}
__device__ __forceinline__ float2 cmulc(float2 a, float wr, float wi) {
    return make_float2(fmaf(a.x, wr, -a.y * wi), fmaf(a.x, wi, a.y * wr));
}
__device__ __forceinline__ float2 cadd(float2 a, float2 b) {
    return make_float2(a.x + b.x, a.y + b.y);
}
__device__ __forceinline__ float2 csub(float2 a, float2 b) {
    return make_float2(a.x - b.x, a.y - b.y);
}
__device__ __forceinline__ void cfma(float& acc, float c, float v) {
    if (c == 0.f) return;
    if (c == 1.f)  { acc += v; return; }
    if (c == -1.f) { acc -= v; return; }
    acc = fmaf(c, v, acc);
}

// 8-pt forward DFT via conjugate-symmetric pairs.
__device__ __forceinline__ void dft8_sym(const float2* u, float2* X) {
    float2 a1 = cadd(u[1], u[7]), b1 = csub(u[1], u[7]);
    float2 a2 = cadd(u[2], u[6]), b2 = csub(u[2], u[6]);
    float2 a3 = cadd(u[3], u[5]), b3 = csub(u[3], u[5]);
    float2 s04 = cadd(u[0], u[4]), d04 = csub(u[0], u[4]);
    X[0] = cadd(cadd(s04, a1), cadd(a2, a3));
    X[4] = cadd(csub(s04, a1), csub(a2, a3));
    {
        float2 p = csub(s04, a2);
        float2 q = csub(b1, b3);
        X[2] = make_float2(p.x + q.y, p.y - q.x);
        X[6] = make_float2(p.x - q.y, p.y + q.x);
    }
#pragma unroll
    for (int m = 1; m <= 3; m += 2) {
        float Px = d04.x, Py = d04.y, Qx = 0.f, Qy = 0.f;
#pragma unroll
        for (int n = 1; n <= 3; n++) {
            const float cR = W16R[(2 * n * m) & 15], cI = W16I[(2 * n * m) & 15];
            const float2 a = (n == 1) ? a1 : (n == 2) ? a2 : a3;
            const float2 b = (n == 1) ? b1 : (n == 2) ? b2 : b3;
            cfma(Px, cR, a.x); cfma(Py, cR, a.y);
            cfma(Qx, cI, b.x); cfma(Qy, cI, b.y);
        }
        X[m]     = make_float2(Px - Qy, Py + Qx);
        X[8 - m] = make_float2(Px + Qy, Py - Qx);
    }
}

// 7-pt forward DFT via conjugate-symmetric pairs.
__device__ __forceinline__ void dft7_sym(const float2* x, float2* X) {
    float2 a1 = cadd(x[1], x[6]), b1 = csub(x[1], x[6]);
    float2 a2 = cadd(x[2], x[5]), b2 = csub(x[2], x[5]);
    float2 a3 = cadd(x[3], x[4]), b3 = csub(x[3], x[4]);
    X[0] = cadd(cadd(x[0], a1), cadd(a2, a3));
#pragma unroll
    for (int k = 1; k <= 3; k++) {
        float Px = x[0].x, Py = x[0].y, Qx = 0.f, Qy = 0.f;
#pragma unroll
        for (int n = 1; n <= 3; n++) {
            const float cR = W7R[(n * k) % 7], cI = W7I[(n * k) % 7];
            const float2 a = (n == 1) ? a1 : (n == 2) ? a2 : a3;
            const float2 b = (n == 1) ? b1 : (n == 2) ? b2 : b3;
            cfma(Px, cR, a.x); cfma(Py, cR, a.y);
            cfma(Qx, cI, b.x); cfma(Qy, cI, b.y);
        }
        X[k]     = make_float2(Px - Qy, Py + Qx);
        X[7 - k] = make_float2(Px + Qy, Py - Qx);
    }
}

// Inner 224-split: 16-pt DFT (radix-2 + sym-8) + W224^{n1*k} twiddle.
// Source: registers. Dest: LDS, packed bf16x2, slot stride 14*mul dwords.
__device__ __forceinline__ void inner16_core(const float2* xin,
                                             unsigned* __restrict__ xbuf,
                                             int base, int mul, int n1) {
    float2 u[8], v[8];
#pragma unroll
    for (int n = 0; n < 8; n++) {
        u[n] = cadd(xin[n], xin[n + 8]);
        float2 w = csub(xin[n], xin[n + 8]);
        v[n] = (n == 0) ? w : cmulc(w, W16R[n], W16I[n]);
    }
    float2 u1w = wexp_neg((float)n1 * (1.0f / 224.0f));
    float2 u2w = wexp_neg((float)n1 * (1.0f / 112.0f));
    {
        float2 Xe[8];
        dft8_sym(u, Xe);
        float2 cur = make_float2(1.f, 0.f);
#pragma unroll
        for (int m = 0; m < 8; m++) {
            float2 z = (m == 0) ? Xe[0] : cmul(Xe[m], cur);
            xbuf[base + (14 * (2 * m)) * mul] = pack_bf2(z.x, z.y);
            cur = cmul(cur, u2w);
        }
    }
    {
        float2 Xo[8];
        dft8_sym(v, Xo);
        float2 cur = u1w;
#pragma unroll
        for (int m = 0; m < 8; m++) {
            float2 z = cmul(Xo[m], cur);
            xbuf[base + (14 * (2 * m + 1)) * mul] = pack_bf2(z.x, z.y);
            cur = cmul(cur, u2w);
        }
    }
}

// ---------------- k_phase: grid (99, 4), 256 threads. x<98: phase GEMM,
// 2 pixels/thread (512-px tile), zern software-prefetch pipeline, writes
// packed bf16x2 plane-0 field. x==98: y0 zloss + defocus tables + counter
// zero, y1..3 mask^2 thirds.
__global__ __launch_bounds__(256, 4) void k_phase(const float* __restrict__ pred,
                                                  const float* __restrict__ target,
                                                  const float* __restrict__ zern,
                                                  const float* __restrict__ mask,
                                                  unsigned* __restrict__ field,
                                                  float* __restrict__ ws) {
    __shared__ __align__(16) float pl[32 * 36];  // stride 36: 16B-aligned quads
    __shared__ float red[256];
    int t = threadIdx.x;
    if (blockIdx.x == 98) {
        int y = blockIdx.y;
        float s = 0.f;
        if (y == 0) {
            if (t == 0) ((int*)ws)[8] = 0;       // stage2 done-counter
            if (t < 224) {                        // separable defocus tables
                float v = lincoord(t);
                float fc = fmaf(2.f * DEFOCUS_RAD, v * v, -DEFOCUS_RAD);
                float fr = 2.f * DEFOCUS_RAD * v * v;
                float sn, cs;
                fast_sincos(fc, &sn, &cs);
                ((float2*)(ws + 16))[t] = make_float2(cs, sn);   // ctab
                fast_sincos(fr, &sn, &cs);
                ((float2*)(ws + 512))[t] = make_float2(cs, sn);  // rtab
            }
            for (int i = t; i < BB * MM; i += 256) {
                float p = pred[i], tg = target[i];
                float dd = p - tg;
                float w = (p * tg < 0.f) ? SIGN_PENALTY : 1.f;
                s = fmaf(dd * dd, w, s);
            }
        } else {
            const int F4 = PP / 4;
            int st = (y - 1) * 4182;
            int en = (y == 3) ? F4 : st + 4182;
            const float4* m4 = (const float4*)mask;
            for (int i = st + t; i < en; i += 256) {
                float4 v = m4[i];
                s = fmaf(v.x, v.x, s); s = fmaf(v.y, v.y, s);
                s = fmaf(v.z, v.z, s); s = fmaf(v.w, v.w, s);
            }
        }
        red[t] = s;
        __syncthreads();
        for (int st = 128; st > 0; st >>= 1) {
            if (t < st) red[t] += red[t + st];
            __syncthreads();
        }
        if (t == 0) {
            if (y == 0) ws[1] = red[0] / (float)(BB * MM);
            else        ws[1 + y] = red[0];
        }
        return;
    }
    int bg = blockIdx.y;
    for (int i = t; i < 32 * MM; i += 256) {
        int j = i / MM, m = i - (i / MM) * MM;
        pl[j * 36 + m] = pred[(bg * 32 + j) * MM + m];
    }
    if (t < 32) pl[t * 36 + 35] = 0.f;   // pad slot (never multiplied)
    __syncthreads();
    int pix0 = blockIdx.x * 512 + t;
    int pix1 = pix0 + 256;
    float acc0[32], acc1[32];
#pragma unroll
    for (int j = 0; j < 32; j++) { acc0[j] = 0.f; acc1[j] = 0.f; }
    const float4* pl4 = (const float4*)pl;     // pl4[j*9 + ch]
    float cz[4], cw[4];
#pragma unroll
    for (int q = 0; q < 4; q++) {              // prologue: chunk 0
        cz[q] = zern[(size_t)q * PP + pix0];
        cw[q] = zern[(size_t)q * PP + pix1];
    }
    for (int ch = 0; ch < 9; ch++) {           // 9 chunks of 4 modes (35+pad)
        float nz[4], nw[4];
        if (ch < 8) {                          // prefetch chunk ch+1
            int nb = (ch + 1) * 4;
#pragma unroll
            for (int q = 0; q < 4; q++) {
                if (nb + q < MM) {
                    nz[q] = zern[(size_t)(nb + q) * PP + pix0];
                    nw[q] = zern[(size_t)(nb + q) * PP + pix1];
                } else { nz[q] = 0.f; nw[q] = 0.f; }
            }
        }
#pragma unroll
        for (int j = 0; j < 32; j++) {         // consume chunk ch
            float4 p4 = pl4[j * 9 + ch];
            acc0[j] = fmaf(p4.x, cz[0], acc0[j]);
            acc0[j] = fmaf(p4.y, cz[1], acc0[j]);
            acc0[j] = fmaf(p4.z, cz[2], acc0[j]);
            acc0[j] = fmaf(p4.w, cz[3], acc0[j]);
            acc1[j] = fmaf(p4.x, cw[0], acc1[j]);
            acc1[j] = fmaf(p4.y, cw[1], acc1[j]);
            acc1[j] = fmaf(p4.z, cw[2], acc1[j]);
            acc1[j] = fmaf(p4.w, cw[3], acc1[j]);
        }
        if (ch < 8) {
#pragma unroll
            for (int q = 0; q < 4; q++) { cz[q] = nz[q]; cw[q] = nw[q]; }
        }
    }
    float mk0 = mask[pix0], mk1 = mask[pix1];
#pragma unroll
    for (int j = 0; j < 32; j++) {
        size_t row = (size_t)(bg * 32 + j) * PP;
        float sn, cs;
        fast_sincos(acc0[j] * mk0, &sn, &cs);
        field[row + pix0] = pack_bf2(mk0 * cs, mk0 * sn);
        fast_sincos(acc1[j] * mk1, &sn, &cs);
        field[row + pix1] = pack_bf2(mk1 * cs, mk1 * sn);
    }
}

// ---------------- stage 1: row DFTs, ONE plane per block, ONE barrier -------
// grid (14, 2, BB): d adjacent in dispatch for L2 field reuse. Inner thread
// (r,n1) loads its 16 pixels; d=1 rotates by ctab[col]*rtab[row] (8 FMA/px,
// f32). Single LDS buffer 14.9KB; (256,5) -> 5 blocks/CU.
__global__ __launch_bounds__(256, 5) void k_stage1(const unsigned* __restrict__ field,
                                                   const float* __restrict__ ws,
                                                   unsigned* __restrict__ T) {
    __shared__ unsigned xs[16 * S1];
    int h0 = blockIdx.x * 16;
    int d = blockIdx.y, b = blockIdx.z;
    int t = threadIdx.x;

    if (t < 224) {
        int r = t / 14, n1 = t - (t / 14) * 14;
        const unsigned* frow = field + (size_t)b * PP + (size_t)(h0 + r) * PSZ;
        float2 x0[16];
        if (d) {
            const float2* ctab = (const float2*)(ws + 16);
            const float2* rtab = (const float2*)(ws + 512);
            float2 crow = rtab[h0 + r];
#pragma unroll
            for (int n = 0; n < 16; n++) {
                int col = n1 + 14 * n;
                float2 f = unpack_bf2(frow[col]);
                float2 rot = cmul(crow, ctab[col]);
                x0[n] = cmul(rot, f);
            }
        } else {
#pragma unroll
            for (int n = 0; n < 16; n++) x0[n] = unpack_bf2(frow[n1 + 14 * n]);
        }
        inner16_core(x0, xs, r * S1 + n1, 1, n1);
    }
    __syncthreads();

    {                                 // outer: 16 rows x 16 k2, one plane
        int r = t >> 4, k2 = t & 15;
        const unsigned* xr = xs + r * S1 + k2 * 14;
        int img = d * BB + b;
        // tile-major: T[img][k1][h0+r][k2]
        unsigned* Tt = T + (((size_t)img * 14) * PSZ + (h0 + r)) * 16 + k2;
        float2 e[7], E[7], O[7];
#pragma unroll
        for (int n = 0; n < 7; n++) e[n] = unpack_bf2(xr[2 * n]);
        dft7_sym(e, E);
#pragma unroll
        for (int n = 0; n < 7; n++) e[n] = unpack_bf2(xr[2 * n + 1]);
        dft7_sym(e, O);
#pragma unroll
        for (int k1 = 0; k1 < 7; k1++) {
            float2 op = (k1 == 0) ? O[0] : cmulc(O[k1], W14R[k1], W14I[k1]);
            float2 s = cadd(E[k1], op), q = csub(E[k1], op);
            Tt[(size_t)k1 * (PSZ * 16)]       = pack_bf2(s.x, s.y);
            Tt[(size_t)(k1 + 7) * (PSZ * 16)] = pack_bf2(q.x, q.y);
        }
    }
}

// ---------------- stage 2: column DFTs + in-register psf loss + finale -----
// Inner DFT reads tile-major T directly from global (coalesced, LLC-hit),
// writes to LDS; outer consumes LDS transposed. Last block (device-scope int
// counter) reduces all partials and writes the output — k_final folded in.
__global__ __launch_bounds__(256, 5) void k_stage2(const unsigned* __restrict__ T,
                                                   const float* __restrict__ psfs,
                                                   float* __restrict__ ws,
                                                   float* __restrict__ partials,
                                                   float* __restrict__ out) {
    __shared__ unsigned xs[224 * S2];
    __shared__ float red[4];
    __shared__ int lastflag;
    int tile = blockIdx.x, b = blockIdx.y, d = blockIdx.z;
    int img = d * BB + b;
    int t = threadIdx.x;
    int k2o = t >> 4, c = t & 15;
    bool act = t < 224;

    const unsigned* Tb = T + ((size_t)img * 14 + tile) * (PSZ * 16);
    const float* inp = psfs + ((size_t)b * 2 + d) * PP;
    int scol = 16 * ((tile + 7) % 14) + c;

    unsigned xr[16];                  // T loads first: they gate the barrier
    if (act) {
#pragma unroll
        for (int n = 0; n < 16; n++) xr[n] = Tb[224 * n + t];
    }
    float pf[14];
#pragma unroll
    for (int j = 0; j < 7; j++) {
        pf[j]     = inp[(size_t)(112 + 16 * j + k2o) * PSZ + scol];
        pf[j + 7] = inp[(size_t)(16 * j + k2o) * PSZ + scol];
    }

    if (act) {                        // inner: 14 n1 x 16 c, reg -> LDS
        float2 x[16];
#pragma unroll
        for (int n = 0; n < 16; n++) x[n] = unpack_bf2(xr[n]);
        inner16_core(x, xs, (t >> 4) * S2 + (t & 15), S2, t >> 4);
    }
    __syncthreads();

    float m2 = ws[2] + ws[3] + ws[4];
    float inv_denom = 1.f / (m2 * (float)PP + EPS_F);  // Parseval denominator

    float lsum = 0.f;
    {                                 // outer: 16 k2 x 16 c, loss in-register
        float2 e[7], E[7], O[7];
#pragma unroll
        for (int n = 0; n < 7; n++) e[n] = unpack_bf2(xs[(k2o * 14 + 2 * n) * S2 + c]);
        dft7_sym(e, E);
#pragma unroll
        for (int n = 0; n < 7; n++) e[n] = unpack_bf2(xs[(k2o * 14 + 2 * n + 1) * S2 + c]);
        dft7_sym(e, O);
#pragma unroll
        for (int k1 = 0; k1 < 7; k1++) {
            float2 op = (k1 == 0) ? O[0] : cmulc(O[k1], W14R[k1], W14I[k1]);
            float2 s = cadd(E[k1], op), q = csub(E[k1], op);
            float ds = fmaf(s.x, s.x, s.y * s.y) * inv_denom - pf[k1];
            float dq = fmaf(q.x, q.x, q.y * q.y) * inv_denom - pf[k1 + 7];
            lsum = fmaf(ds, ds, lsum);
            lsum = fmaf(dq, dq, lsum);
        }
    }
#pragma unroll
    for (int off = 32; off > 0; off >>= 1)
        lsum += __shfl_down(lsum, off, 64);
    if ((t & 63) == 0) red[t >> 6] = lsum;
    __syncthreads();
    if (t == 0) {
        partials[(blockIdx.z * BB + blockIdx.y) * 14 + blockIdx.x] =
            red[0] + red[1] + red[2] + red[3];
        __threadfence();              // release: partial visible device-wide
        int old = atomicAdd((int*)ws + 8, 1);
        lastflag = (old == N_PARTIALS - 1);
    }
    __syncthreads();
    if (lastflag) {                   // final reduce by the last block
        __threadfence();              // acquire
        float s = 0.f;
        for (int i = t; i < N_PARTIALS; i += 256) s += partials[i];
#pragma unroll
        for (int off = 32; off > 0; off >>= 1)
            s += __shfl_down(s, off, 64);
        if ((t & 63) == 0) red[t >> 6] = s;
        __syncthreads();
        if (t == 0) {
            float recon = (red[0] + red[1] + red[2] + red[3]) /
                          (float)((size_t)BB * PP);
            out[0] = ws[1] + RECON_WEIGHT * recon;
        }
    }
}

extern "C" void kernel_launch(void* const* d_in, const int* in_sizes, int n_in,
                              void* d_out, int out_size, void* d_ws, size_t ws_size,
                              hipStream_t stream) {
    const float* pred   = (const float*)d_in[0];
    const float* target = (const float*)d_in[1];
    const float* psfs   = (const float*)d_in[2];
    const float* zern   = (const float*)d_in[3];
    const float* mask   = (const float*)d_in[4];

    float*    ws       = (float*)d_ws;
    unsigned* field    = (unsigned*)(ws + WS_PHASE_OFF);
    float*    partials = ws + WS_PHASE_OFF;   // aliases field (dead after stage1)
    unsigned* T        = (unsigned*)(ws + WS_T_OFF);
    float*    out      = (float*)d_out;

    k_phase<<<dim3(99, 4), 256, 0, stream>>>(pred, target, zern, mask, field, ws);
    k_stage1<<<dim3(14, 2, BB), 256, 0, stream>>>(field, ws, T);
    k_stage2<<<dim3(14, BB, 2), 256, 0, stream>>>(T, psfs, ws, partials, out);
}

// Round 7
// 156.127 us; speedup vs baseline: 1.8456x; 1.8456x over previous
//
#include <hip/hip_runtime.h>
#include <math.h>

#define BB 128
#define MM 35
#define PSZ 224
#define PP (PSZ*PSZ)          // 50176
#define SIGN_PENALTY 10.0f
#define RECON_WEIGHT 0.4f
#define DEFOCUS_RAD 1.0f
#define EPS_F 1e-8f
#define INV2PI 0.15915494309189535f

// CT: 224 = 14*16.  n = 14*n2 + n1; k = 16*k1 + k2.
// R19 = R18 post-mortem: REVERT the k_final fold (it was -136us!).
//   R18's last-block finale put a device-scope __threadfence() in all 3584
//   stage2 blocks. Per-XCD L2s are not cross-coherent on MI355X -> the
//   release fence flushes L2 state per block; k_stage2 went ~15us -> 180us
//   (420 GB/s, FETCH 75MB, latency-bound). RULE (extends R5-R7): no
//   device-scope fence/atomic finale inside a hot kernel; a serialized
//   1-block k_final (~3us) is far cheaper than per-block coherence traffic.
//   KEPT from R18: k_phase zern software-prefetch pipeline (2px/thread,
//   256 thr, grid (99,4)) — isolated this round.
// Budget model: harness poison fills (~41us each) are a fixed floor in the
// timed window; our kernels sum ~30-40us. Diminishing-returns regime.
// Prior structure: separable defocus tables (ws[16..960)); stage1 one plane
// per block grid (14,2,BB), (256,5); tile-major T [img][tile14][h224][c16];
// stage2 global-direct + in-reg loss; v_cvt_pk_bf16_f32 packing.
// Spill rule (R10/R11): >~32 floats cross-phase state = scratch.

// ws layout (floats):
//   [1] z_loss  [2..4] mask^2 partials (3)
//   [16..464)  ctab: 224 x float2 e^{i(2D vx^2 - D)}
//   [512..960) rtab: 224 x float2 e^{i(2D vy^2)}
//   [2048 ..) field [B][P][P] packed bf16x2 — dead after stage1; partials alias
//   [T_OFF ..) T [2*B][14][224][16] packed bf16x2
#define WS_PHASE_OFF    2048
#define WS_T_OFF        (WS_PHASE_OFF + BB*PP)
#define N_PARTIALS      (14*BB*2)
#define S1 233            // stage1 LDS row stride (dwords) — odd: 2-way banks
#define S2 20             // stage2 LDS slot-row stride (dwords)

static constexpr float W16R[16] = {
    1.0f, 0.9238795325f, 0.7071067812f, 0.3826834324f, 0.0f,
    -0.3826834324f, -0.7071067812f, -0.9238795325f, -1.0f,
    -0.9238795325f, -0.7071067812f, -0.3826834324f, 0.0f,
    0.3826834324f, 0.7071067812f, 0.9238795325f};
static constexpr float W16I[16] = {
    0.0f, -0.3826834324f, -0.7071067812f, -0.9238795325f, -1.0f,
    -0.9238795325f, -0.7071067812f, -0.3826834324f, 0.0f,
    0.3826834324f, 0.7071067812f, 0.9238795325f, 1.0f,
    0.9238795325f, 0.7071067812f, 0.3826834324f};
static constexpr float W7R[7] = {
    1.0f, 0.6234898019f, -0.2225209340f, -0.9009688679f,
    -0.9009688679f, -0.2225209340f, 0.6234898019f};
static constexpr float W7I[7] = {
    0.0f, -0.7818314825f, -0.9749279122f, -0.4338837391f,
    0.4338837391f, 0.9749279122f, 0.7818314825f};
static constexpr float W14R[7] = {
    1.0f, 0.9009688679f, 0.6234898019f, 0.2225209340f, -0.2225209340f,
    -0.6234898019f, -0.9009688679f};
static constexpr float W14I[7] = {
    0.0f, -0.4338837391f, -0.7818314825f, -0.9749279122f, -0.9749279122f,
    -0.7818314825f, -0.4338837391f};

__device__ __forceinline__ float lincoord(int i) {
    return -1.0f + 2.0f * (float)i / (float)(PSZ - 1);
}
__device__ __forceinline__ void fast_sincos(float x, float* s, float* c) {
    float rv = x * INV2PI;
    rv -= floorf(rv);
    *s = __builtin_amdgcn_sinf(rv);
    *c = __builtin_amdgcn_cosf(rv);
}
__device__ __forceinline__ float2 wexp_neg(float frac) {
    float rv = -frac;
    rv -= floorf(rv);
    return make_float2(__builtin_amdgcn_cosf(rv), __builtin_amdgcn_sinf(rv));
}
__device__ __forceinline__ unsigned pack_bf2(float a, float b) {
    // D[15:0]=bf16(a), D[31:16]=bf16(b) — single VALU op (RNE)
    unsigned r;
    asm("v_cvt_pk_bf16_f32 %0, %1, %2" : "=v"(r) : "v"(a), "v"(b));
    return r;
}
__device__ __forceinline__ float2 unpack_bf2(unsigned v) {
    return make_float2(__uint_as_float(v << 16), __uint_as_float(v & 0xffff0000u));
}
__device__ __forceinline__ float2 cmul(float2 a, float2 b) {
    return make_float2(fmaf(a.x, b.x, -a.y * b.y), fmaf(a.x, b.y, a.y * b.x));
}
__device__ __forceinline__ float2 cmulc(float2 a, float wr, float wi) {
    return make_float2(fmaf(a.x, wr, -a.y * wi), fmaf(a.x, wi, a.y * wr));
}
__device__ __forceinline__ float2 cadd(float2 a, float2 b) {
    return make_float2(a.x + b.x, a.y + b.y);
}
__device__ __forceinline__ float2 csub(float2 a, float2 b) {
    return make_float2(a.x - b.x, a.y - b.y);
}
__device__ __forceinline__ void cfma(float& acc, float c, float v) {
    if (c == 0.f) return;
    if (c == 1.f)  { acc += v; return; }
    if (c == -1.f) { acc -= v; return; }
    acc = fmaf(c, v, acc);
}

// 8-pt forward DFT via conjugate-symmetric pairs.
__device__ __forceinline__ void dft8_sym(const float2* u, float2* X) {
    float2 a1 = cadd(u[1], u[7]), b1 = csub(u[1], u[7]);
    float2 a2 = cadd(u[2], u[6]), b2 = csub(u[2], u[6]);
    float2 a3 = cadd(u[3], u[5]), b3 = csub(u[3], u[5]);
    float2 s04 = cadd(u[0], u[4]), d04 = csub(u[0], u[4]);
    X[0] = cadd(cadd(s04, a1), cadd(a2, a3));
    X[4] = cadd(csub(s04, a1), csub(a2, a3));
    {
        float2 p = csub(s04, a2);
        float2 q = csub(b1, b3);
        X[2] = make_float2(p.x + q.y, p.y - q.x);
        X[6] = make_float2(p.x - q.y, p.y + q.x);
    }
#pragma unroll
    for (int m = 1; m <= 3; m += 2) {
        float Px = d04.x, Py = d04.y, Qx = 0.f, Qy = 0.f;
#pragma unroll
        for (int n = 1; n <= 3; n++) {
            const float cR = W16R[(2 * n * m) & 15], cI = W16I[(2 * n * m) & 15];
            const float2 a = (n == 1) ? a1 : (n == 2) ? a2 : a3;
            const float2 b = (n == 1) ? b1 : (n == 2) ? b2 : b3;
            cfma(Px, cR, a.x); cfma(Py, cR, a.y);
            cfma(Qx, cI, b.x); cfma(Qy, cI, b.y);
        }
        X[m]     = make_float2(Px - Qy, Py + Qx);
        X[8 - m] = make_float2(Px + Qy, Py - Qx);
    }
}

// 7-pt forward DFT via conjugate-symmetric pairs.
__device__ __forceinline__ void dft7_sym(const float2* x, float2* X) {
    float2 a1 = cadd(x[1], x[6]), b1 = csub(x[1], x[6]);
    float2 a2 = cadd(x[2], x[5]), b2 = csub(x[2], x[5]);
    float2 a3 = cadd(x[3], x[4]), b3 = csub(x[3], x[4]);
    X[0] = cadd(cadd(x[0], a1), cadd(a2, a3));
#pragma unroll
    for (int k = 1; k <= 3; k++) {
        float Px = x[0].x, Py = x[0].y, Qx = 0.f, Qy = 0.f;
#pragma unroll
        for (int n = 1; n <= 3; n++) {
            const float cR = W7R[(n * k) % 7], cI = W7I[(n * k) % 7];
            const float2 a = (n == 1) ? a1 : (n == 2) ? a2 : a3;
            const float2 b = (n == 1) ? b1 : (n == 2) ? b2 : b3;
            cfma(Px, cR, a.x); cfma(Py, cR, a.y);
            cfma(Qx, cI, b.x); cfma(Qy, cI, b.y);
        }
        X[k]     = make_float2(Px - Qy, Py + Qx);
        X[7 - k] = make_float2(Px + Qy, Py - Qx);
    }
}

// Inner 224-split: 16-pt DFT (radix-2 + sym-8) + W224^{n1*k} twiddle.
// Source: registers. Dest: LDS, packed bf16x2, slot stride 14*mul dwords.
__device__ __forceinline__ void inner16_core(const float2* xin,
                                             unsigned* __restrict__ xbuf,
                                             int base, int mul, int n1) {
    float2 u[8], v[8];
#pragma unroll
    for (int n = 0; n < 8; n++) {
        u[n] = cadd(xin[n], xin[n + 8]);
        float2 w = csub(xin[n], xin[n + 8]);
        v[n] = (n == 0) ? w : cmulc(w, W16R[n], W16I[n]);
    }
    float2 u1w = wexp_neg((float)n1 * (1.0f / 224.0f));
    float2 u2w = wexp_neg((float)n1 * (1.0f / 112.0f));
    {
        float2 Xe[8];
        dft8_sym(u, Xe);
        float2 cur = make_float2(1.f, 0.f);
#pragma unroll
        for (int m = 0; m < 8; m++) {
            float2 z = (m == 0) ? Xe[0] : cmul(Xe[m], cur);
            xbuf[base + (14 * (2 * m)) * mul] = pack_bf2(z.x, z.y);
            cur = cmul(cur, u2w);
        }
    }
    {
        float2 Xo[8];
        dft8_sym(v, Xo);
        float2 cur = u1w;
#pragma unroll
        for (int m = 0; m < 8; m++) {
            float2 z = cmul(Xo[m], cur);
            xbuf[base + (14 * (2 * m + 1)) * mul] = pack_bf2(z.x, z.y);
            cur = cmul(cur, u2w);
        }
    }
}

// ---------------- k_phase: grid (99, 4), 256 threads. x<98: phase GEMM,
// 2 pixels/thread (512-px tile), zern software-prefetch pipeline, writes
// packed bf16x2 plane-0 field. x==98: y0 zloss + defocus tables,
// y1..3 mask^2 thirds.
__global__ __launch_bounds__(256, 4) void k_phase(const float* __restrict__ pred,
                                                  const float* __restrict__ target,
                                                  const float* __restrict__ zern,
                                                  const float* __restrict__ mask,
                                                  unsigned* __restrict__ field,
                                                  float* __restrict__ ws) {
    __shared__ __align__(16) float pl[32 * 36];  // stride 36: 16B-aligned quads
    __shared__ float red[256];
    int t = threadIdx.x;
    if (blockIdx.x == 98) {
        int y = blockIdx.y;
        float s = 0.f;
        if (y == 0) {
            if (t < 224) {                        // separable defocus tables
                float v = lincoord(t);
                float fc = fmaf(2.f * DEFOCUS_RAD, v * v, -DEFOCUS_RAD);
                float fr = 2.f * DEFOCUS_RAD * v * v;
                float sn, cs;
                fast_sincos(fc, &sn, &cs);
                ((float2*)(ws + 16))[t] = make_float2(cs, sn);   // ctab
                fast_sincos(fr, &sn, &cs);
                ((float2*)(ws + 512))[t] = make_float2(cs, sn);  // rtab
            }
            for (int i = t; i < BB * MM; i += 256) {
                float p = pred[i], tg = target[i];
                float dd = p - tg;
                float w = (p * tg < 0.f) ? SIGN_PENALTY : 1.f;
                s = fmaf(dd * dd, w, s);
            }
        } else {
            const int F4 = PP / 4;
            int st = (y - 1) * 4182;
            int en = (y == 3) ? F4 : st + 4182;
            const float4* m4 = (const float4*)mask;
            for (int i = st + t; i < en; i += 256) {
                float4 v = m4[i];
                s = fmaf(v.x, v.x, s); s = fmaf(v.y, v.y, s);
                s = fmaf(v.z, v.z, s); s = fmaf(v.w, v.w, s);
            }
        }
        red[t] = s;
        __syncthreads();
        for (int st = 128; st > 0; st >>= 1) {
            if (t < st) red[t] += red[t + st];
            __syncthreads();
        }
        if (t == 0) {
            if (y == 0) ws[1] = red[0] / (float)(BB * MM);
            else        ws[1 + y] = red[0];
        }
        return;
    }
    int bg = blockIdx.y;
    for (int i = t; i < 32 * MM; i += 256) {
        int j = i / MM, m = i - (i / MM) * MM;
        pl[j * 36 + m] = pred[(bg * 32 + j) * MM + m];
    }
    if (t < 32) pl[t * 36 + 35] = 0.f;   // pad slot (never multiplied)
    __syncthreads();
    int pix0 = blockIdx.x * 512 + t;
    int pix1 = pix0 + 256;
    float acc0[32], acc1[32];
#pragma unroll
    for (int j = 0; j < 32; j++) { acc0[j] = 0.f; acc1[j] = 0.f; }
    const float4* pl4 = (const float4*)pl;     // pl4[j*9 + ch]
    float cz[4], cw[4];
#pragma unroll
    for (int q = 0; q < 4; q++) {              // prologue: chunk 0
        cz[q] = zern[(size_t)q * PP + pix0];
        cw[q] = zern[(size_t)q * PP + pix1];
    }
    for (int ch = 0; ch < 9; ch++) {           // 9 chunks of 4 modes (35+pad)
        float nz[4], nw[4];
        if (ch < 8) {                          // prefetch chunk ch+1
            int nb = (ch + 1) * 4;
#pragma unroll
            for (int q = 0; q < 4; q++) {
                if (nb + q < MM) {
                    nz[q] = zern[(size_t)(nb + q) * PP + pix0];
                    nw[q] = zern[(size_t)(nb + q) * PP + pix1];
                } else { nz[q] = 0.f; nw[q] = 0.f; }
            }
        }
#pragma unroll
        for (int j = 0; j < 32; j++) {         // consume chunk ch
            float4 p4 = pl4[j * 9 + ch];
            acc0[j] = fmaf(p4.x, cz[0], acc0[j]);
            acc0[j] = fmaf(p4.y, cz[1], acc0[j]);
            acc0[j] = fmaf(p4.z, cz[2], acc0[j]);
            acc0[j] = fmaf(p4.w, cz[3], acc0[j]);
            acc1[j] = fmaf(p4.x, cw[0], acc1[j]);
            acc1[j] = fmaf(p4.y, cw[1], acc1[j]);
            acc1[j] = fmaf(p4.z, cw[2], acc1[j]);
            acc1[j] = fmaf(p4.w, cw[3], acc1[j]);
        }
        if (ch < 8) {
#pragma unroll
            for (int q = 0; q < 4; q++) { cz[q] = nz[q]; cw[q] = nw[q]; }
        }
    }
    float mk0 = mask[pix0], mk1 = mask[pix1];
#pragma unroll
    for (int j = 0; j < 32; j++) {
        size_t row = (size_t)(bg * 32 + j) * PP;
        float sn, cs;
        fast_sincos(acc0[j] * mk0, &sn, &cs);
        field[row + pix0] = pack_bf2(mk0 * cs, mk0 * sn);
        fast_sincos(acc1[j] * mk1, &sn, &cs);
        field[row + pix1] = pack_bf2(mk1 * cs, mk1 * sn);
    }
}

// ---------------- stage 1: row DFTs, ONE plane per block, ONE barrier -------
// grid (14, 2, BB): d adjacent in dispatch for L2 field reuse. Inner thread
// (r,n1) loads its 16 pixels; d=1 rotates by ctab[col]*rtab[row] (8 FMA/px,
// f32). Single LDS buffer 14.9KB; (256,5) -> 5 blocks/CU.
__global__ __launch_bounds__(256, 5) void k_stage1(const unsigned* __restrict__ field,
                                                   const float* __restrict__ ws,
                                                   unsigned* __restrict__ T) {
    __shared__ unsigned xs[16 * S1];
    int h0 = blockIdx.x * 16;
    int d = blockIdx.y, b = blockIdx.z;
    int t = threadIdx.x;

    if (t < 224) {
        int r = t / 14, n1 = t - (t / 14) * 14;
        const unsigned* frow = field + (size_t)b * PP + (size_t)(h0 + r) * PSZ;
        float2 x0[16];
        if (d) {
            const float2* ctab = (const float2*)(ws + 16);
            const float2* rtab = (const float2*)(ws + 512);
            float2 crow = rtab[h0 + r];
#pragma unroll
            for (int n = 0; n < 16; n++) {
                int col = n1 + 14 * n;
                float2 f = unpack_bf2(frow[col]);
                float2 rot = cmul(crow, ctab[col]);
                x0[n] = cmul(rot, f);
            }
        } else {
#pragma unroll
            for (int n = 0; n < 16; n++) x0[n] = unpack_bf2(frow[n1 + 14 * n]);
        }
        inner16_core(x0, xs, r * S1 + n1, 1, n1);
    }
    __syncthreads();

    {                                 // outer: 16 rows x 16 k2, one plane
        int r = t >> 4, k2 = t & 15;
        const unsigned* xr = xs + r * S1 + k2 * 14;
        int img = d * BB + b;
        // tile-major: T[img][k1][h0+r][k2]
        unsigned* Tt = T + (((size_t)img * 14) * PSZ + (h0 + r)) * 16 + k2;
        float2 e[7], E[7], O[7];
#pragma unroll
        for (int n = 0; n < 7; n++) e[n] = unpack_bf2(xr[2 * n]);
        dft7_sym(e, E);
#pragma unroll
        for (int n = 0; n < 7; n++) e[n] = unpack_bf2(xr[2 * n + 1]);
        dft7_sym(e, O);
#pragma unroll
        for (int k1 = 0; k1 < 7; k1++) {
            float2 op = (k1 == 0) ? O[0] : cmulc(O[k1], W14R[k1], W14I[k1]);
            float2 s = cadd(E[k1], op), q = csub(E[k1], op);
            Tt[(size_t)k1 * (PSZ * 16)]       = pack_bf2(s.x, s.y);
            Tt[(size_t)(k1 + 7) * (PSZ * 16)] = pack_bf2(q.x, q.y);
        }
    }
}

// ---------------- stage 2: column DFTs + in-register psf loss ----------------
// Inner DFT reads tile-major T directly from global (coalesced, LLC-hit),
// writes to LDS; outer consumes LDS transposed. T loads issued first.
__global__ __launch_bounds__(256, 5) void k_stage2(const unsigned* __restrict__ T,
                                                   const float* __restrict__ psfs,
                                                   const float* __restrict__ ws,
                                                   float* __restrict__ partials) {
    __shared__ unsigned xs[224 * S2];
    __shared__ float red[4];
    int tile = blockIdx.x, b = blockIdx.y, d = blockIdx.z;
    int img = d * BB + b;
    int t = threadIdx.x;
    int k2o = t >> 4, c = t & 15;
    bool act = t < 224;

    const unsigned* Tb = T + ((size_t)img * 14 + tile) * (PSZ * 16);
    const float* inp = psfs + ((size_t)b * 2 + d) * PP;
    int scol = 16 * ((tile + 7) % 14) + c;

    unsigned xr[16];                  // T loads first: they gate the barrier
    if (act) {
#pragma unroll
        for (int n = 0; n < 16; n++) xr[n] = Tb[224 * n + t];
    }
    float pf[14];
#pragma unroll
    for (int j = 0; j < 7; j++) {
        pf[j]     = inp[(size_t)(112 + 16 * j + k2o) * PSZ + scol];
        pf[j + 7] = inp[(size_t)(16 * j + k2o) * PSZ + scol];
    }

    if (act) {                        // inner: 14 n1 x 16 c, reg -> LDS
        float2 x[16];
#pragma unroll
        for (int n = 0; n < 16; n++) x[n] = unpack_bf2(xr[n]);
        inner16_core(x, xs, (t >> 4) * S2 + (t & 15), S2, t >> 4);
    }
    __syncthreads();

    float m2 = ws[2] + ws[3] + ws[4];
    float inv_denom = 1.f / (m2 * (float)PP + EPS_F);  // Parseval denominator

    float lsum = 0.f;
    {                                 // outer: 16 k2 x 16 c, loss in-register
        float2 e[7], E[7], O[7];
#pragma unroll
        for (int n = 0; n < 7; n++) e[n] = unpack_bf2(xs[(k2o * 14 + 2 * n) * S2 + c]);
        dft7_sym(e, E);
#pragma unroll
        for (int n = 0; n < 7; n++) e[n] = unpack_bf2(xs[(k2o * 14 + 2 * n + 1) * S2 + c]);
        dft7_sym(e, O);
#pragma unroll
        for (int k1 = 0; k1 < 7; k1++) {
            float2 op = (k1 == 0) ? O[0] : cmulc(O[k1], W14R[k1], W14I[k1]);
            float2 s = cadd(E[k1], op), q = csub(E[k1], op);
            float ds = fmaf(s.x, s.x, s.y * s.y) * inv_denom - pf[k1];
            float dq = fmaf(q.x, q.x, q.y * q.y) * inv_denom - pf[k1 + 7];
            lsum = fmaf(ds, ds, lsum);
            lsum = fmaf(dq, dq, lsum);
        }
    }
#pragma unroll
    for (int off = 32; off > 0; off >>= 1)
        lsum += __shfl_down(lsum, off, 64);
    if ((t & 63) == 0) red[t >> 6] = lsum;
    __syncthreads();
    if (t == 0)
        partials[(blockIdx.z * BB + blockIdx.y) * 14 + blockIdx.x] =
            red[0] + red[1] + red[2] + red[3];
}

// ---------------- final ----------------
__global__ void k_final(const float* __restrict__ ws,
                        const float* __restrict__ partials,
                        float* __restrict__ out) {
    __shared__ float red[256];
    float s = 0.f;
    for (int i = threadIdx.x; i < N_PARTIALS; i += 256) s += partials[i];
    red[threadIdx.x] = s;
    __syncthreads();
    for (int st = 128; st > 0; st >>= 1) {
        if (threadIdx.x < st) red[threadIdx.x] += red[threadIdx.x + st];
        __syncthreads();
    }
    if (threadIdx.x == 0) {
        float recon = red[0] / (float)((size_t)BB * PP);
        out[0] = ws[1] + RECON_WEIGHT * recon;
    }
}

extern "C" void kernel_launch(void* const* d_in, const int* in_sizes, int n_in,
                              void* d_out, int out_size, void* d_ws, size_t ws_size,
                              hipStream_t stream) {
    const float* pred   = (const float*)d_in[0];
    const float* target = (const float*)d_in[1];
    const float* psfs   = (const float*)d_in[2];
    const float* zern   = (const float*)d_in[3];
    const float* mask   = (const float*)d_in[4];

    float*    ws       = (float*)d_ws;
    unsigned* field    = (unsigned*)(ws + WS_PHASE_OFF);
    float*    partials = ws + WS_PHASE_OFF;   // aliases field (dead after stage1)
    unsigned* T        = (unsigned*)(ws + WS_T_OFF);
    float*    out      = (float*)d_out;

    k_phase<<<dim3(99, 4), 256, 0, stream>>>(pred, target, zern, mask, field, ws);
    k_stage1<<<dim3(14, 2, BB), 256, 0, stream>>>(field, ws, T);
    k_stage2<<<dim3(14, BB, 2), 256, 0, stream>>>(T, psfs, ws, partials);
    k_final<<<1, 256, 0, stream>>>(ws, partials, out);
}

// Round 8
// 153.354 us; speedup vs baseline: 1.8790x; 1.0181x over previous
//
#include <hip/hip_runtime.h>
#include <math.h>

#define BB 128
#define MM 35
#define PSZ 224
#define PP (PSZ*PSZ)          // 50176
#define SIGN_PENALTY 10.0f
#define RECON_WEIGHT 0.4f
#define DEFOCUS_RAD 1.0f
#define EPS_F 1e-8f
#define INV2PI 0.15915494309189535f

// CT: 224 = 14*16.  n = 14*n2 + n1; k = 16*k1 + k2.
// R20 = best-measured configuration, locked in:
//   k_phase: R17 version (128 thr, grid (197,4), 2px/thread, NO prefetch).
//            R19 isolated R18's prefetch variant: 156.1 vs R17's 152.3 —
//            conditional prefetch + reg pressure cost more than latency won.
//   stage1/stage2/final: R16/R17 form (separable defocus tables, one plane
//            per block, tile-major T, global-direct stage2, 1-block finale).
// RULES learned: (R18) no device-scope fence/atomic finale in hot kernels —
// per-XCD L2 non-coherence makes each fence flush L2 (~-136us). (R5-R7) no
// same-address float finale atomics. (R10/R11) >~32 floats cross-phase
// state/thread = scratch spill.
// Budget: harness poison fills (~41us ea) are a fixed floor in the timed
// window; our 4 kernels sum ~60-70us. Plateau: remaining deltas ±1-3us.

// ws layout (floats):
//   [1] z_loss  [2..4] mask^2 partials (3)
//   [16..464)  ctab: 224 x float2 e^{i(2D vx^2 - D)}
//   [512..960) rtab: 224 x float2 e^{i(2D vy^2)}
//   [2048 ..) field [B][P][P] packed bf16x2 — dead after stage1; partials alias
//   [T_OFF ..) T [2*B][14][224][16] packed bf16x2
#define WS_PHASE_OFF    2048
#define WS_T_OFF        (WS_PHASE_OFF + BB*PP)
#define N_PARTIALS      (14*BB*2)
#define S1 233            // stage1 LDS row stride (dwords) — odd: 2-way banks
#define S2 20             // stage2 LDS slot-row stride (dwords)

static constexpr float W16R[16] = {
    1.0f, 0.9238795325f, 0.7071067812f, 0.3826834324f, 0.0f,
    -0.3826834324f, -0.7071067812f, -0.9238795325f, -1.0f,
    -0.9238795325f, -0.7071067812f, -0.3826834324f, 0.0f,
    0.3826834324f, 0.7071067812f, 0.9238795325f};
static constexpr float W16I[16] = {
    0.0f, -0.3826834324f, -0.7071067812f, -0.9238795325f, -1.0f,
    -0.9238795325f, -0.7071067812f, -0.3826834324f, 0.0f,
    0.3826834324f, 0.7071067812f, 0.9238795325f, 1.0f,
    0.9238795325f, 0.7071067812f, 0.3826834324f};
static constexpr float W7R[7] = {
    1.0f, 0.6234898019f, -0.2225209340f, -0.9009688679f,
    -0.9009688679f, -0.2225209340f, 0.6234898019f};
static constexpr float W7I[7] = {
    0.0f, -0.7818314825f, -0.9749279122f, -0.4338837391f,
    0.4338837391f, 0.9749279122f, 0.7818314825f};
static constexpr float W14R[7] = {
    1.0f, 0.9009688679f, 0.6234898019f, 0.2225209340f, -0.2225209340f,
    -0.6234898019f, -0.9009688679f};
static constexpr float W14I[7] = {
    0.0f, -0.4338837391f, -0.7818314825f, -0.9749279122f, -0.9749279122f,
    -0.7818314825f, -0.4338837391f};

__device__ __forceinline__ float lincoord(int i) {
    return -1.0f + 2.0f * (float)i / (float)(PSZ - 1);
}
__device__ __forceinline__ void fast_sincos(float x, float* s, float* c) {
    float rv = x * INV2PI;
    rv -= floorf(rv);
    *s = __builtin_amdgcn_sinf(rv);
    *c = __builtin_amdgcn_cosf(rv);
}
__device__ __forceinline__ float2 wexp_neg(float frac) {
    float rv = -frac;
    rv -= floorf(rv);
    return make_float2(__builtin_amdgcn_cosf(rv), __builtin_amdgcn_sinf(rv));
}
__device__ __forceinline__ unsigned pack_bf2(float a, float b) {
    // D[15:0]=bf16(a), D[31:16]=bf16(b) — single VALU op (RNE)
    unsigned r;
    asm("v_cvt_pk_bf16_f32 %0, %1, %2" : "=v"(r) : "v"(a), "v"(b));
    return r;
}
__device__ __forceinline__ float2 unpack_bf2(unsigned v) {
    return make_float2(__uint_as_float(v << 16), __uint_as_float(v & 0xffff0000u));
}
__device__ __forceinline__ float2 cmul(float2 a, float2 b) {
    return make_float2(fmaf(a.x, b.x, -a.y * b.y), fmaf(a.x, b.y, a.y * b.x));
}
__device__ __forceinline__ float2 cmulc(float2 a, float wr, float wi) {
    return make_float2(fmaf(a.x, wr, -a.y * wi), fmaf(a.x, wi, a.y * wr));
}
__device__ __forceinline__ float2 cadd(float2 a, float2 b) {
    return make_float2(a.x + b.x, a.y + b.y);
}
__device__ __forceinline__ float2 csub(float2 a, float2 b) {
    return make_float2(a.x - b.x, a.y - b.y);
}
__device__ __forceinline__ void cfma(float& acc, float c, float v) {
    if (c == 0.f) return;
    if (c == 1.f)  { acc += v; return; }
    if (c == -1.f) { acc -= v; return; }
    acc = fmaf(c, v, acc);
}

// 8-pt forward DFT via conjugate-symmetric pairs.
__device__ __forceinline__ void dft8_sym(const float2* u, float2* X) {
    float2 a1 = cadd(u[1], u[7]), b1 = csub(u[1], u[7]);
    float2 a2 = cadd(u[2], u[6]), b2 = csub(u[2], u[6]);
    float2 a3 = cadd(u[3], u[5]), b3 = csub(u[3], u[5]);
    float2 s04 = cadd(u[0], u[4]), d04 = csub(u[0], u[4]);
    X[0] = cadd(cadd(s04, a1), cadd(a2, a3));
    X[4] = cadd(csub(s04, a1), csub(a2, a3));
    {
        float2 p = csub(s04, a2);
        float2 q = csub(b1, b3);
        X[2] = make_float2(p.x + q.y, p.y - q.x);
        X[6] = make_float2(p.x - q.y, p.y + q.x);
    }
#pragma unroll
    for (int m = 1; m <= 3; m += 2) {
        float Px = d04.x, Py = d04.y, Qx = 0.f, Qy = 0.f;
#pragma unroll
        for (int n = 1; n <= 3; n++) {
            const float cR = W16R[(2 * n * m) & 15], cI = W16I[(2 * n * m) & 15];
            const float2 a = (n == 1) ? a1 : (n == 2) ? a2 : a3;
            const float2 b = (n == 1) ? b1 : (n == 2) ? b2 : b3;
            cfma(Px, cR, a.x); cfma(Py, cR, a.y);
            cfma(Qx, cI, b.x); cfma(Qy, cI, b.y);
        }
        X[m]     = make_float2(Px - Qy, Py + Qx);
        X[8 - m] = make_float2(Px + Qy, Py - Qx);
    }
}

// 7-pt forward DFT via conjugate-symmetric pairs.
__device__ __forceinline__ void dft7_sym(const float2* x, float2* X) {
    float2 a1 = cadd(x[1], x[6]), b1 = csub(x[1], x[6]);
    float2 a2 = cadd(x[2], x[5]), b2 = csub(x[2], x[5]);
    float2 a3 = cadd(x[3], x[4]), b3 = csub(x[3], x[4]);
    X[0] = cadd(cadd(x[0], a1), cadd(a2, a3));
#pragma unroll
    for (int k = 1; k <= 3; k++) {
        float Px = x[0].x, Py = x[0].y, Qx = 0.f, Qy = 0.f;
#pragma unroll
        for (int n = 1; n <= 3; n++) {
            const float cR = W7R[(n * k) % 7], cI = W7I[(n * k) % 7];
            const float2 a = (n == 1) ? a1 : (n == 2) ? a2 : a3;
            const float2 b = (n == 1) ? b1 : (n == 2) ? b2 : b3;
            cfma(Px, cR, a.x); cfma(Py, cR, a.y);
            cfma(Qx, cI, b.x); cfma(Qy, cI, b.y);
        }
        X[k]     = make_float2(Px - Qy, Py + Qx);
        X[7 - k] = make_float2(Px + Qy, Py - Qx);
    }
}

// Inner 224-split: 16-pt DFT (radix-2 + sym-8) + W224^{n1*k} twiddle.
// Source: registers. Dest: LDS, packed bf16x2, slot stride 14*mul dwords.
__device__ __forceinline__ void inner16_core(const float2* xin,
                                             unsigned* __restrict__ xbuf,
                                             int base, int mul, int n1) {
    float2 u[8], v[8];
#pragma unroll
    for (int n = 0; n < 8; n++) {
        u[n] = cadd(xin[n], xin[n + 8]);
        float2 w = csub(xin[n], xin[n + 8]);
        v[n] = (n == 0) ? w : cmulc(w, W16R[n], W16I[n]);
    }
    float2 u1w = wexp_neg((float)n1 * (1.0f / 224.0f));
    float2 u2w = wexp_neg((float)n1 * (1.0f / 112.0f));
    {
        float2 Xe[8];
        dft8_sym(u, Xe);
        float2 cur = make_float2(1.f, 0.f);
#pragma unroll
        for (int m = 0; m < 8; m++) {
            float2 z = (m == 0) ? Xe[0] : cmul(Xe[m], cur);
            xbuf[base + (14 * (2 * m)) * mul] = pack_bf2(z.x, z.y);
            cur = cmul(cur, u2w);
        }
    }
    {
        float2 Xo[8];
        dft8_sym(v, Xo);
        float2 cur = u1w;
#pragma unroll
        for (int m = 0; m < 8; m++) {
            float2 z = cmul(Xo[m], cur);
            xbuf[base + (14 * (2 * m + 1)) * mul] = pack_bf2(z.x, z.y);
            cur = cmul(cur, u2w);
        }
    }
}

// ---------------- k_phase: grid (197, 4), 128 threads. x<196: phase GEMM,
// 2 pixels/thread (256-px tile), writes packed bf16x2 plane-0 field.
// x==196: y0 zloss + defocus tables, y1..3 mask^2 thirds.
__global__ __launch_bounds__(128) void k_phase(const float* __restrict__ pred,
                                               const float* __restrict__ target,
                                               const float* __restrict__ zern,
                                               const float* __restrict__ mask,
                                               unsigned* __restrict__ field,
                                               float* __restrict__ ws) {
    __shared__ __align__(16) float pl[32 * 36];  // stride 36: 16B-aligned quads
    __shared__ float red[128];
    int t = threadIdx.x;
    if (blockIdx.x == 196) {
        int y = blockIdx.y;
        float s = 0.f;
        if (y == 0) {
            for (int i = t; i < 224; i += 128) {  // separable defocus tables
                float v = lincoord(i);
                float fc = fmaf(2.f * DEFOCUS_RAD, v * v, -DEFOCUS_RAD);
                float fr = 2.f * DEFOCUS_RAD * v * v;
                float sn, cs;
                fast_sincos(fc, &sn, &cs);
                ((float2*)(ws + 16))[i] = make_float2(cs, sn);   // ctab
                fast_sincos(fr, &sn, &cs);
                ((float2*)(ws + 512))[i] = make_float2(cs, sn);  // rtab
            }
            for (int i = t; i < BB * MM; i += 128) {
                float p = pred[i], tg = target[i];
                float dd = p - tg;
                float w = (p * tg < 0.f) ? SIGN_PENALTY : 1.f;
                s = fmaf(dd * dd, w, s);
            }
        } else {
            const int F4 = PP / 4;
            int st = (y - 1) * 4182;
            int en = (y == 3) ? F4 : st + 4182;
            const float4* m4 = (const float4*)mask;
            for (int i = st + t; i < en; i += 128) {
                float4 v = m4[i];
                s = fmaf(v.x, v.x, s); s = fmaf(v.y, v.y, s);
                s = fmaf(v.z, v.z, s); s = fmaf(v.w, v.w, s);
            }
        }
        red[t] = s;
        __syncthreads();
        for (int st = 64; st > 0; st >>= 1) {
            if (t < st) red[t] += red[t + st];
            __syncthreads();
        }
        if (t == 0) {
            if (y == 0) ws[1] = red[0] / (float)(BB * MM);
            else        ws[1 + y] = red[0];
        }
        return;
    }
    int bg = blockIdx.y;
    for (int i = t; i < 32 * MM; i += 128) {
        int j = i / MM, m = i - (i / MM) * MM;
        pl[j * 36 + m] = pred[(bg * 32 + j) * MM + m];
    }
    if (t < 32) pl[t * 36 + 35] = 0.f;   // pad slot (never multiplied)
    __syncthreads();
    int pix0 = blockIdx.x * 256 + t;     // t in 0..127
    int pix1 = pix0 + 128;
    float acc0[32], acc1[32];
#pragma unroll
    for (int j = 0; j < 32; j++) { acc0[j] = 0.f; acc1[j] = 0.f; }
    const float4* pl4 = (const float4*)pl;     // pl4[j*9 + mb/4]
    for (int mb = 0; mb < 32; mb += 4) {       // 8 chunks of 4 modes
        float z0 = zern[(size_t)(mb + 0) * PP + pix0];
        float z1 = zern[(size_t)(mb + 1) * PP + pix0];
        float z2 = zern[(size_t)(mb + 2) * PP + pix0];
        float z3 = zern[(size_t)(mb + 3) * PP + pix0];
        float w0 = zern[(size_t)(mb + 0) * PP + pix1];
        float w1 = zern[(size_t)(mb + 1) * PP + pix1];
        float w2 = zern[(size_t)(mb + 2) * PP + pix1];
        float w3 = zern[(size_t)(mb + 3) * PP + pix1];
#pragma unroll
        for (int j = 0; j < 32; j++) {
            float4 p4 = pl4[j * 9 + (mb >> 2)];
            acc0[j] = fmaf(p4.x, z0, acc0[j]);
            acc0[j] = fmaf(p4.y, z1, acc0[j]);
            acc0[j] = fmaf(p4.z, z2, acc0[j]);
            acc0[j] = fmaf(p4.w, z3, acc0[j]);
            acc1[j] = fmaf(p4.x, w0, acc1[j]);
            acc1[j] = fmaf(p4.y, w1, acc1[j]);
            acc1[j] = fmaf(p4.z, w2, acc1[j]);
            acc1[j] = fmaf(p4.w, w3, acc1[j]);
        }
    }
    {                                          // tail: modes 32..34
        float z0 = zern[(size_t)32 * PP + pix0];
        float z1 = zern[(size_t)33 * PP + pix0];
        float z2 = zern[(size_t)34 * PP + pix0];
        float w0 = zern[(size_t)32 * PP + pix1];
        float w1 = zern[(size_t)33 * PP + pix1];
        float w2 = zern[(size_t)34 * PP + pix1];
#pragma unroll
        for (int j = 0; j < 32; j++) {
            float4 p4 = pl4[j * 9 + 8];
            acc0[j] = fmaf(p4.x, z0, acc0[j]);
            acc0[j] = fmaf(p4.y, z1, acc0[j]);
            acc0[j] = fmaf(p4.z, z2, acc0[j]);
            acc1[j] = fmaf(p4.x, w0, acc1[j]);
            acc1[j] = fmaf(p4.y, w1, acc1[j]);
            acc1[j] = fmaf(p4.z, w2, acc1[j]);
        }
    }
    float mk0 = mask[pix0], mk1 = mask[pix1];
#pragma unroll
    for (int j = 0; j < 32; j++) {
        size_t row = (size_t)(bg * 32 + j) * PP;
        float sn, cs;
        fast_sincos(acc0[j] * mk0, &sn, &cs);
        field[row + pix0] = pack_bf2(mk0 * cs, mk0 * sn);
        fast_sincos(acc1[j] * mk1, &sn, &cs);
        field[row + pix1] = pack_bf2(mk1 * cs, mk1 * sn);
    }
}

// ---------------- stage 1: row DFTs, ONE plane per block, ONE barrier -------
// grid (14, 2, BB): d adjacent in dispatch for L2 field reuse. Inner thread
// (r,n1) loads its 16 pixels; d=1 rotates by ctab[col]*rtab[row] (8 FMA/px,
// f32). Single LDS buffer 14.9KB; (256,5) -> 5 blocks/CU.
__global__ __launch_bounds__(256, 5) void k_stage1(const unsigned* __restrict__ field,
                                                   const float* __restrict__ ws,
                                                   unsigned* __restrict__ T) {
    __shared__ unsigned xs[16 * S1];
    int h0 = blockIdx.x * 16;
    int d = blockIdx.y, b = blockIdx.z;
    int t = threadIdx.x;

    if (t < 224) {
        int r = t / 14, n1 = t - (t / 14) * 14;
        const unsigned* frow = field + (size_t)b * PP + (size_t)(h0 + r) * PSZ;
        float2 x0[16];
        if (d) {
            const float2* ctab = (const float2*)(ws + 16);
            const float2* rtab = (const float2*)(ws + 512);
            float2 crow = rtab[h0 + r];
#pragma unroll
            for (int n = 0; n < 16; n++) {
                int col = n1 + 14 * n;
                float2 f = unpack_bf2(frow[col]);
                float2 rot = cmul(crow, ctab[col]);
                x0[n] = cmul(rot, f);
            }
        } else {
#pragma unroll
            for (int n = 0; n < 16; n++) x0[n] = unpack_bf2(frow[n1 + 14 * n]);
        }
        inner16_core(x0, xs, r * S1 + n1, 1, n1);
    }
    __syncthreads();

    {                                 // outer: 16 rows x 16 k2, one plane
        int r = t >> 4, k2 = t & 15;
        const unsigned* xr = xs + r * S1 + k2 * 14;
        int img = d * BB + b;
        // tile-major: T[img][k1][h0+r][k2]
        unsigned* Tt = T + (((size_t)img * 14) * PSZ + (h0 + r)) * 16 + k2;
        float2 e[7], E[7], O[7];
#pragma unroll
        for (int n = 0; n < 7; n++) e[n] = unpack_bf2(xr[2 * n]);
        dft7_sym(e, E);
#pragma unroll
        for (int n = 0; n < 7; n++) e[n] = unpack_bf2(xr[2 * n + 1]);
        dft7_sym(e, O);
#pragma unroll
        for (int k1 = 0; k1 < 7; k1++) {
            float2 op = (k1 == 0) ? O[0] : cmulc(O[k1], W14R[k1], W14I[k1]);
            float2 s = cadd(E[k1], op), q = csub(E[k1], op);
            Tt[(size_t)k1 * (PSZ * 16)]       = pack_bf2(s.x, s.y);
            Tt[(size_t)(k1 + 7) * (PSZ * 16)] = pack_bf2(q.x, q.y);
        }
    }
}

// ---------------- stage 2: column DFTs + in-register psf loss ----------------
// Inner DFT reads tile-major T directly from global (coalesced, LLC-hit),
// writes to LDS; outer consumes LDS transposed. T loads issued first.
__global__ __launch_bounds__(256, 5) void k_stage2(const unsigned* __restrict__ T,
                                                   const float* __restrict__ psfs,
                                                   const float* __restrict__ ws,
                                                   float* __restrict__ partials) {
    __shared__ unsigned xs[224 * S2];
    __shared__ float red[4];
    int tile = blockIdx.x, b = blockIdx.y, d = blockIdx.z;
    int img = d * BB + b;
    int t = threadIdx.x;
    int k2o = t >> 4, c = t & 15;
    bool act = t < 224;

    const unsigned* Tb = T + ((size_t)img * 14 + tile) * (PSZ * 16);
    const float* inp = psfs + ((size_t)b * 2 + d) * PP;
    int scol = 16 * ((tile + 7) % 14) + c;

    unsigned xr[16];                  // T loads first: they gate the barrier
    if (act) {
#pragma unroll
        for (int n = 0; n < 16; n++) xr[n] = Tb[224 * n + t];
    }
    float pf[14];
#pragma unroll
    for (int j = 0; j < 7; j++) {
        pf[j]     = inp[(size_t)(112 + 16 * j + k2o) * PSZ + scol];
        pf[j + 7] = inp[(size_t)(16 * j + k2o) * PSZ + scol];
    }

    if (act) {                        // inner: 14 n1 x 16 c, reg -> LDS
        float2 x[16];
#pragma unroll
        for (int n = 0; n < 16; n++) x[n] = unpack_bf2(xr[n]);
        inner16_core(x, xs, (t >> 4) * S2 + (t & 15), S2, t >> 4);
    }
    __syncthreads();

    float m2 = ws[2] + ws[3] + ws[4];
    float inv_denom = 1.f / (m2 * (float)PP + EPS_F);  // Parseval denominator

    float lsum = 0.f;
    {                                 // outer: 16 k2 x 16 c, loss in-register
        float2 e[7], E[7], O[7];
#pragma unroll
        for (int n = 0; n < 7; n++) e[n] = unpack_bf2(xs[(k2o * 14 + 2 * n) * S2 + c]);
        dft7_sym(e, E);
#pragma unroll
        for (int n = 0; n < 7; n++) e[n] = unpack_bf2(xs[(k2o * 14 + 2 * n + 1) * S2 + c]);
        dft7_sym(e, O);
#pragma unroll
        for (int k1 = 0; k1 < 7; k1++) {
            float2 op = (k1 == 0) ? O[0] : cmulc(O[k1], W14R[k1], W14I[k1]);
            float2 s = cadd(E[k1], op), q = csub(E[k1], op);
            float ds = fmaf(s.x, s.x, s.y * s.y) * inv_denom - pf[k1];
            float dq = fmaf(q.x, q.x, q.y * q.y) * inv_denom - pf[k1 + 7];
            lsum = fmaf(ds, ds, lsum);
            lsum = fmaf(dq, dq, lsum);
        }
    }
#pragma unroll
    for (int off = 32; off > 0; off >>= 1)
        lsum += __shfl_down(lsum, off, 64);
    if ((t & 63) == 0) red[t >> 6] = lsum;
    __syncthreads();
    if (t == 0)
        partials[(blockIdx.z * BB + blockIdx.y) * 14 + blockIdx.x] =
            red[0] + red[1] + red[2] + red[3];
}

// ---------------- final ----------------
__global__ void k_final(const float* __restrict__ ws,
                        const float* __restrict__ partials,
                        float* __restrict__ out) {
    __shared__ float red[256];
    float s = 0.f;
    for (int i = threadIdx.x; i < N_PARTIALS; i += 256) s += partials[i];
    red[threadIdx.x] = s;
    __syncthreads();
    for (int st = 128; st > 0; st >>= 1) {
        if (threadIdx.x < st) red[threadIdx.x] += red[threadIdx.x + st];
        __syncthreads();
    }
    if (threadIdx.x == 0) {
        float recon = red[0] / (float)((size_t)BB * PP);
        out[0] = ws[1] + RECON_WEIGHT * recon;
    }
}

extern "C" void kernel_launch(void* const* d_in, const int* in_sizes, int n_in,
                              void* d_out, int out_size, void* d_ws, size_t ws_size,
                              hipStream_t stream) {
    const float* pred   = (const float*)d_in[0];
    const float* target = (const float*)d_in[1];
    const float* psfs   = (const float*)d_in[2];
    const float* zern   = (const float*)d_in[3];
    const float* mask   = (const float*)d_in[4];

    float*    ws       = (float*)d_ws;
    unsigned* field    = (unsigned*)(ws + WS_PHASE_OFF);
    float*    partials = ws + WS_PHASE_OFF;   // aliases field (dead after stage1)
    unsigned* T        = (unsigned*)(ws + WS_T_OFF);
    float*    out      = (float*)d_out;

    k_phase<<<dim3(197, 4), 128, 0, stream>>>(pred, target, zern, mask, field, ws);
    k_stage1<<<dim3(14, 2, BB), 256, 0, stream>>>(field, ws, T);
    k_stage2<<<dim3(14, BB, 2), 256, 0, stream>>>(T, psfs, ws, partials);
    k_final<<<1, 256, 0, stream>>>(ws, partials, out);
}